// Round 1
// baseline (241.713 us; speedup 1.0000x reference)
//
#include <hip/hip_runtime.h>
#include <hip/hip_bf16.h>

typedef short short8 __attribute__((ext_vector_type(8)));
typedef float f32x4 __attribute__((ext_vector_type(4)));

#define NB 4096   // batch rows
#define KZ 2048   // concat K  (IN + OUT)
#define NG 1024   // per-gate output cols
#define BM 128
#define BNG 32    // per-gate cols per block (x4 gates = 128 tile cols)
#define BK 64

__device__ __forceinline__ unsigned short f2bf(float f) {
  unsigned int u = __float_as_uint(f);
  u += 0x7FFFu + ((u >> 16) & 1u);   // round-to-nearest-even
  return (unsigned short)(u >> 16);
}
__device__ __forceinline__ float bf2f(unsigned short s) {
  return __uint_as_float(((unsigned int)s) << 16);
}

__device__ __forceinline__ void gload_lds16(const void* g, void* l) {
  __builtin_amdgcn_global_load_lds(
      (__attribute__((address_space(1))) void*)g,
      (__attribute__((address_space(3))) void*)l, 16, 0, 0);
}

__device__ __forceinline__ float sigm(float x) { return 1.f / (1.f + __expf(-x)); }
__device__ __forceinline__ float tanh_fast(float x) {
  float e = __expf(-2.f * fabsf(x));
  float r = (1.f - e) / (1.f + e);
  return copysignf(r, x);
}

// ---- fuse concat([x,h]) + bf16 hi/lo split:  zh/zl [4096][2048] ----
__global__ void zsplit_kernel(const float* __restrict__ x, const float* __restrict__ h,
                              unsigned short* __restrict__ zh, unsigned short* __restrict__ zl) {
  int idx = blockIdx.x * 256 + threadIdx.x;
  int e = idx << 2;                 // 4 elems / thread
  int r = e >> 11;
  int k = e & (KZ - 1);
  const float* src = (k < 1024) ? (x + ((size_t)r << 10) + k)
                                : (h + ((size_t)r << 10) + (k - 1024));
  float4 v = *reinterpret_cast<const float4*>(src);
  float vf[4] = {v.x, v.y, v.z, v.w};
  unsigned short hh[4], ll[4];
#pragma unroll
  for (int j = 0; j < 4; ++j) {
    unsigned short hi = f2bf(vf[j]);
    unsigned short lo = f2bf(vf[j] - bf2f(hi));
    hh[j] = hi; ll[j] = lo;
  }
  uint2 H = make_uint2((unsigned)hh[0] | ((unsigned)hh[1] << 16),
                       (unsigned)hh[2] | ((unsigned)hh[3] << 16));
  uint2 L = make_uint2((unsigned)ll[0] | ((unsigned)ll[1] << 16),
                       (unsigned)ll[2] | ((unsigned)ll[3] << 16));
  *reinterpret_cast<uint2*>(zh + e) = H;
  *reinterpret_cast<uint2*>(zl + e) = L;
}

// ---- transpose + split weights:  wt[g*1024+n][k] = w_g[k][n]  (hi/lo) ----
__global__ void wsplit_kernel(const float* __restrict__ w0, const float* __restrict__ w1,
                              const float* __restrict__ w2, const float* __restrict__ w3,
                              unsigned short* __restrict__ wh, unsigned short* __restrict__ wl) {
  __shared__ float tile[32][33];
  int g = blockIdx.z;
  const float* w = (g == 0) ? w0 : (g == 1) ? w1 : (g == 2) ? w2 : w3;
  int k0 = blockIdx.x << 5;
  int n0 = blockIdx.y << 5;
  int t = threadIdx.x;
  int rk = t >> 3, q = t & 7;       // read 32(k) x 32(n): one float4 each
  float4 v = *reinterpret_cast<const float4*>(w + (size_t)(k0 + rk) * NG + n0 + (q << 2));
  tile[rk][(q << 2) + 0] = v.x;
  tile[rk][(q << 2) + 1] = v.y;
  tile[rk][(q << 2) + 2] = v.z;
  tile[rk][(q << 2) + 3] = v.w;
  __syncthreads();
  int n = t >> 3, kq = t & 7;       // write: 4 consecutive k for one n
  unsigned short hs[4], ls[4];
#pragma unroll
  for (int j = 0; j < 4; ++j) {
    float f = tile[(kq << 2) + j][n];
    unsigned short hi = f2bf(f);
    unsigned short lo = f2bf(f - bf2f(hi));
    hs[j] = hi; ls[j] = lo;
  }
  size_t o = (size_t)((g << 10) + n0 + n) * KZ + k0 + (kq << 2);
  uint2 H = make_uint2((unsigned)hs[0] | ((unsigned)hs[1] << 16),
                       (unsigned)hs[2] | ((unsigned)hs[3] << 16));
  uint2 L = make_uint2((unsigned)ls[0] | ((unsigned)ls[1] << 16),
                       (unsigned)ls[2] | ((unsigned)ls[3] << 16));
  *reinterpret_cast<uint2*>(wh + o) = H;
  *reinterpret_cast<uint2*>(wl + o) = L;
}

// ---- fused 4-gate GEMM + LSTM epilogue ----
// Tile: 128 rows x (4 gates x 32 cols). 4 waves stacked on M, each 32x128.
// K total = 3 segments x 2048 (hi*hi, hi*lo, lo*hi), BK=64.
__global__ __launch_bounds__(256) void lstm_gemm_kernel(
    const unsigned short* __restrict__ zh, const unsigned short* __restrict__ zl,
    const unsigned short* __restrict__ wh, const unsigned short* __restrict__ wl,
    const float* __restrict__ c_in, const float* __restrict__ bf_,
    const float* __restrict__ bi_, const float* __restrict__ bc_,
    const float* __restrict__ bo_, float* __restrict__ out) {
  __shared__ unsigned short As[BM * BK];   // [row 0..127][k 0..63], slot-swizzled
  __shared__ unsigned short Bs[BM * BK];   // [tr = gate*32+n][k], slot-swizzled
  const int t = threadIdx.x;
  const int lane = t & 63;
  const int wid = t >> 6;
  const int ncol0 = blockIdx.x * BNG;
  const int brow0 = blockIdx.y * BM;

  f32x4 acc[2][8];
#pragma unroll
  for (int m = 0; m < 2; ++m)
#pragma unroll
    for (int n = 0; n < 8; ++n) acc[m][n] = (f32x4){0.f, 0.f, 0.f, 0.f};

  // staging constants: LDS byte o = j*4096 + t*16; row = o>>7; slot' = (o>>4)&7.
  // data placed at slot' comes from source slot slot'^(row&7)  (XOR swizzle, G4).
  int aeb[4], beb[4], ldsb[4];
#pragma unroll
  for (int j = 0; j < 4; ++j) {
    int o = (j << 12) + (t << 4);
    int row = o >> 7;
    int sl = ((o >> 4) & 7) ^ (row & 7);
    aeb[j] = (brow0 + row) * KZ + (sl << 3);
    int wtrow = ((row >> 5) << 10) + ncol0 + (row & 31);   // gate*1024 + n
    beb[j] = wtrow * KZ + (sl << 3);
    ldsb[j] = (j << 12) + (wid << 10);   // wave-uniform LDS base
  }
  char* Asb = (char*)As;
  char* Bsb = (char*)Bs;

  for (int seg = 0; seg < 3; ++seg) {
    const unsigned short* asrc = (seg == 2) ? zl : zh;
    const unsigned short* bsrc = (seg == 1) ? wl : wh;
    for (int kt = 0; kt < 32; ++kt) {
      const int kk = kt << 6;
#pragma unroll
      for (int j = 0; j < 4; ++j) {
        gload_lds16(asrc + aeb[j] + kk, Asb + ldsb[j]);
        gload_lds16(bsrc + beb[j] + kk, Bsb + ldsb[j]);
      }
      __syncthreads();
#pragma unroll
      for (int ks = 0; ks < 2; ++ks) {
        short8 a[2], b[8];
        const int kq = (ks << 2) + (lane >> 4);
#pragma unroll
        for (int m = 0; m < 2; ++m) {
          int row = (wid << 5) + (m << 4) + (lane & 15);
          a[m] = *reinterpret_cast<const short8*>(&As[(row << 6) + ((kq ^ (row & 7)) << 3)]);
        }
#pragma unroll
        for (int n = 0; n < 8; ++n) {
          int tr = (n << 4) + (lane & 15);
          b[n] = *reinterpret_cast<const short8*>(&Bs[(tr << 6) + ((kq ^ (tr & 7)) << 3)]);
        }
#pragma unroll
        for (int m = 0; m < 2; ++m)
#pragma unroll
          for (int n = 0; n < 8; ++n)
            acc[m][n] = __builtin_amdgcn_mfma_f32_16x16x32_bf16(a[m], b[n], acc[m][n], 0, 0, 0);
      }
      __syncthreads();
    }
  }

  // epilogue: col-frags 0-1=f, 2-3=i, 4-5=g, 6-7=o  (all lane-local)
  const int l15 = lane & 15;
  const int l4 = lane >> 4;
#pragma unroll
  for (int mf = 0; mf < 2; ++mf) {
#pragma unroll
    for (int nh = 0; nh < 2; ++nh) {
      const int ng = ncol0 + (nh << 4) + l15;
      const float vbf = bf_[ng], vbi = bi_[ng], vbc = bc_[ng], vbo = bo_[ng];
#pragma unroll
      for (int r = 0; r < 4; ++r) {
        const int row = brow0 + (wid << 5) + (mf << 4) + (l4 << 2) + r;
        const float fp = acc[mf][0 + nh][r] + vbf;
        const float ip = acc[mf][2 + nh][r] + vbi;
        const float gp = acc[mf][4 + nh][r] + vbc;
        const float op = acc[mf][6 + nh][r] + vbo;
        const float co = c_in[(size_t)row * NG + ng];
        const float cnew = co * sigm(fp) + sigm(ip) * tanh_fast(gp);
        out[(size_t)row * NG + ng] = tanh_fast(cnew) * sigm(op);
      }
    }
  }
}

extern "C" void kernel_launch(void* const* d_in, const int* in_sizes, int n_in,
                              void* d_out, int out_size, void* d_ws, size_t ws_size,
                              hipStream_t stream) {
  const float* x   = (const float*)d_in[0];
  const float* h   = (const float*)d_in[1];
  const float* c   = (const float*)d_in[2];
  const float* w_f = (const float*)d_in[3];
  const float* b_f = (const float*)d_in[4];
  const float* w_i = (const float*)d_in[5];
  const float* b_i = (const float*)d_in[6];
  const float* w_c = (const float*)d_in[7];
  const float* b_c = (const float*)d_in[8];
  const float* w_o = (const float*)d_in[9];
  const float* b_o = (const float*)d_in[10];
  float* out = (float*)d_out;

  unsigned short* zh = (unsigned short*)d_ws;                 // 16 MB each
  unsigned short* zl = zh + (size_t)NB * KZ;
  unsigned short* wh = zl + (size_t)NB * KZ;
  unsigned short* wl = wh + (size_t)NB * KZ;                  // total 64 MB ws

  zsplit_kernel<<<(NB * KZ / 4) / 256, 256, 0, stream>>>(x, h, zh, zl);
  wsplit_kernel<<<dim3(KZ / 32, NG / 32, 4), 256, 0, stream>>>(w_f, w_i, w_c, w_o, wh, wl);
  lstm_gemm_kernel<<<dim3(NG / BNG, NB / BM), 256, 0, stream>>>(zh, zl, wh, wl, c,
                                                                b_f, b_i, b_c, b_o, out);
}

// Round 2
// 209.399 us; speedup vs baseline: 1.1543x; 1.1543x over previous
//
#include <hip/hip_runtime.h>
#include <hip/hip_bf16.h>

typedef short short8 __attribute__((ext_vector_type(8)));
typedef float f32x4 __attribute__((ext_vector_type(4)));

#define NB 4096   // batch rows
#define KZ 2048   // concat K (IN + OUT)
#define NG 1024   // per-gate output cols
#define NT 96     // K-tiles: 3 segments x (2048/64)

__device__ __forceinline__ unsigned short f2bf(float f) {
  unsigned int u = __float_as_uint(f);
  u += 0x7FFFu + ((u >> 16) & 1u);   // RNE
  return (unsigned short)(u >> 16);
}
__device__ __forceinline__ float bf2f(unsigned short s) {
  return __uint_as_float(((unsigned int)s) << 16);
}
__device__ __forceinline__ void gload_lds16(const void* g, void* l) {
  __builtin_amdgcn_global_load_lds(
      (__attribute__((address_space(1))) void*)g,
      (__attribute__((address_space(3))) void*)l, 16, 0, 0);
}
__device__ __forceinline__ float sigm(float x) { return 1.f / (1.f + __expf(-x)); }
__device__ __forceinline__ float tanh_fast(float x) {
  float e = __expf(-2.f * fabsf(x));
  float r = (1.f - e) / (1.f + e);
  return copysignf(r, x);
}

// ---- concat([x,h]) + bf16 hi/lo split -> zh/zl [4096][2048] ----
__global__ void zsplit_kernel(const float* __restrict__ x, const float* __restrict__ h,
                              unsigned short* __restrict__ zh, unsigned short* __restrict__ zl) {
  int idx = blockIdx.x * 256 + threadIdx.x;
  int e = idx << 2;
  int r = e >> 11;
  int k = e & (KZ - 1);
  const float* src = (k < 1024) ? (x + ((size_t)r << 10) + k)
                                : (h + ((size_t)r << 10) + (k - 1024));
  float4 v = *reinterpret_cast<const float4*>(src);
  float vf[4] = {v.x, v.y, v.z, v.w};
  unsigned short hh[4], ll[4];
#pragma unroll
  for (int j = 0; j < 4; ++j) {
    unsigned short hi = f2bf(vf[j]);
    unsigned short lo = f2bf(vf[j] - bf2f(hi));
    hh[j] = hi; ll[j] = lo;
  }
  uint2 H = make_uint2((unsigned)hh[0] | ((unsigned)hh[1] << 16),
                       (unsigned)hh[2] | ((unsigned)hh[3] << 16));
  uint2 L = make_uint2((unsigned)ll[0] | ((unsigned)ll[1] << 16),
                       (unsigned)ll[2] | ((unsigned)ll[3] << 16));
  *reinterpret_cast<uint2*>(zh + e) = H;
  *reinterpret_cast<uint2*>(zl + e) = L;
}

// ---- transpose + split weights into gate-interleaved packed rows ----
// p = (n>>6)<<8 | ((n>>4)&3)<<6 | g<<4 | (n&15)   (so each wave's 64 cols = 4 gates x 16)
__global__ void wsplit_kernel(const float* __restrict__ w0, const float* __restrict__ w1,
                              const float* __restrict__ w2, const float* __restrict__ w3,
                              unsigned short* __restrict__ wh, unsigned short* __restrict__ wl) {
  __shared__ float tile[32][33];
  int g = blockIdx.z;
  const float* w = (g == 0) ? w0 : (g == 1) ? w1 : (g == 2) ? w2 : w3;
  int k0 = blockIdx.x << 5;
  int n0 = blockIdx.y << 5;
  int t = threadIdx.x;
  int rk = t >> 3, q = t & 7;
  float4 v = *reinterpret_cast<const float4*>(w + (size_t)(k0 + rk) * NG + n0 + (q << 2));
  tile[rk][(q << 2) + 0] = v.x;
  tile[rk][(q << 2) + 1] = v.y;
  tile[rk][(q << 2) + 2] = v.z;
  tile[rk][(q << 2) + 3] = v.w;
  __syncthreads();
  int n = t >> 3, kq = t & 7;
  unsigned short hs[4], ls[4];
#pragma unroll
  for (int j = 0; j < 4; ++j) {
    float f = tile[(kq << 2) + j][n];
    unsigned short hi = f2bf(f);
    unsigned short lo = f2bf(f - bf2f(hi));
    hs[j] = hi; ls[j] = lo;
  }
  int nn = n0 + n;
  int p = ((nn >> 6) << 8) | (((nn >> 4) & 3) << 6) | (g << 4) | (nn & 15);
  size_t o = (size_t)p * KZ + k0 + (kq << 2);
  uint2 H = make_uint2((unsigned)hs[0] | ((unsigned)hs[1] << 16),
                       (unsigned)hs[2] | ((unsigned)hs[3] << 16));
  uint2 L = make_uint2((unsigned)ls[0] | ((unsigned)ls[1] << 16),
                       (unsigned)ls[2] | ((unsigned)ls[3] << 16));
  *reinterpret_cast<uint2*>(wh + o) = H;
  *reinterpret_cast<uint2*>(wl + o) = L;
}

#define MFMA(a, b, c) __builtin_amdgcn_mfma_f32_16x16x32_bf16((a), (b), (c), 0, 0, 0)

// ---- 256x256 8-phase fused 4-gate GEMM + LSTM epilogue ----
// 8 waves (2M x 4N), per-wave 128x64; K = 3 segments x 2048, BK=64.
__global__ __launch_bounds__(512, 2) void lstm_gemm256_kernel(
    const unsigned short* __restrict__ zh, const unsigned short* __restrict__ zl,
    const unsigned short* __restrict__ wh, const unsigned short* __restrict__ wl,
    const float* __restrict__ c_in, const float* __restrict__ bf_,
    const float* __restrict__ bi_, const float* __restrict__ bc_,
    const float* __restrict__ bo_, float* __restrict__ out) {
  __shared__ unsigned short As[2 * 2 * 8192];   // 2 dbuf x 2 halves x 128x64, 64 KB
  __shared__ unsigned short Bs[2 * 2 * 8192];   // 64 KB
  const int t = threadIdx.x;
  const int lane = t & 63;
  const int wid = t >> 6;
  const int wr = wid >> 2;          // 0..1 (M)
  const int wc = wid & 3;           // 0..3 (N)
  const int l15 = lane & 15;
  const int l4 = lane >> 4;
  const int bx = blockIdx.x;        // 0..15 col-block (64 per-gate cols)
  const int by = blockIdx.y;        // 0..15 row-block
  const int brow0 = by << 8;
  const int pcol0 = bx << 8;

  char* AsB = (char*)As;
  char* BsB = (char*)Bs;

  // stage addressing: load j of a half-tile: LDS byte o = j*8192 + t*16 (linear dest)
  // row = o>>7, dest slot s' = (o>>4)&7 holds source slot s'^(row&7)  (XOR swizzle)
  int aoff[2], boff[2];
#pragma unroll
  for (int j = 0; j < 2; ++j) {
    int row = (j << 6) + (t >> 3);
    int sl = (t & 7) ^ (row & 7);
    aoff[j] = (brow0 + row) * KZ + (sl << 3);
    boff[j] = (pcol0 + row) * KZ + (sl << 3);
  }
  const int ldsw = wid << 10;       // wave-uniform lane-base (HW adds lane*16)

  auto STAGE = [&](int s, int hx) {
    if (s >= NT) return;
    const int c = s & 1;
    const int seg = s >> 5;
    const int kk = (s & 31) << 6;
    if (hx < 2) {
      const unsigned short* src = (seg == 2) ? zl : zh;
      const int hb = hx * (128 * KZ);
      const int lb = c * 32768 + hx * 16384;
#pragma unroll
      for (int j = 0; j < 2; ++j)
        gload_lds16(src + aoff[j] + hb + kk, AsB + lb + (j << 13) + ldsw);
    } else {
      const unsigned short* src = (seg == 1) ? wl : wh;
      const int hb = (hx - 2) * (128 * KZ);
      const int lb = c * 32768 + (hx - 2) * 16384;
#pragma unroll
      for (int j = 0; j < 2; ++j)
        gload_lds16(src + boff[j] + hb + kk, BsB + lb + (j << 13) + ldsw);
    }
  };

  f32x4 acc[8][4];
#pragma unroll
  for (int m = 0; m < 8; ++m)
#pragma unroll
    for (int n = 0; n < 4; ++n) acc[m][n] = (f32x4){0.f, 0.f, 0.f, 0.f};

  // per-lane read constants: row&7 == l15&7 for all frags
  const int rx = l15 & 7;
  const int sx0 = (l4 ^ rx) << 4;          // ks=0 slot byte offset
  const int sx1 = ((4 + l4) ^ rx) << 4;    // ks=1
  const int aB = l15 << 7;                           // + m*2048
  const int bB = ((wc & 1) << 13) + (l15 << 7);      // + n*2048

  // prologue: tile0 (4 halves) + tile1 A halves
  STAGE(0, 0); STAGE(0, 1); STAGE(0, 2); STAGE(0, 3);
  STAGE(1, 0); STAGE(1, 1);
  asm volatile("s_waitcnt vmcnt(4)" ::: "memory");
  __builtin_amdgcn_s_barrier();

  for (int kt = 0; kt < NT; ++kt) {
    const int c = kt & 1;
    const int abase = c * 32768 + wr * 16384;
    const int bbase = c * 32768 + (wc >> 1) * 16384;
    short8 aL[4][2], aH[4][2], bL[2][2], bH[2][2];

    // ---- P1: read aL (m0-3) + bL (n0-1); stage (t+1, B-h0) ----
#pragma unroll
    for (int m = 0; m < 4; ++m) {
      aL[m][0] = *reinterpret_cast<const short8*>(AsB + abase + aB + (m << 11) + sx0);
      aL[m][1] = *reinterpret_cast<const short8*>(AsB + abase + aB + (m << 11) + sx1);
    }
#pragma unroll
    for (int n = 0; n < 2; ++n) {
      bL[n][0] = *reinterpret_cast<const short8*>(BsB + bbase + bB + (n << 11) + sx0);
      bL[n][1] = *reinterpret_cast<const short8*>(BsB + bbase + bB + (n << 11) + sx1);
    }
    STAGE(kt + 1, 2);
    __builtin_amdgcn_s_barrier();
    asm volatile("s_waitcnt lgkmcnt(0)" ::: "memory");
    __builtin_amdgcn_s_setprio(1);
#pragma unroll
    for (int m = 0; m < 4; ++m)
#pragma unroll
      for (int n = 0; n < 2; ++n) {
        acc[m][n] = MFMA(aL[m][0], bL[n][0], acc[m][n]);
        acc[m][n] = MFMA(aL[m][1], bL[n][1], acc[m][n]);
      }
    __builtin_amdgcn_s_setprio(0);
    __builtin_amdgcn_s_barrier();

    // ---- P2: read bH (n2-3); stage (t+1, B-h1) ----
#pragma unroll
    for (int n = 0; n < 2; ++n) {
      bH[n][0] = *reinterpret_cast<const short8*>(BsB + bbase + bB + ((n + 2) << 11) + sx0);
      bH[n][1] = *reinterpret_cast<const short8*>(BsB + bbase + bB + ((n + 2) << 11) + sx1);
    }
    STAGE(kt + 1, 3);
    __builtin_amdgcn_s_barrier();
    asm volatile("s_waitcnt lgkmcnt(0)" ::: "memory");
    __builtin_amdgcn_s_setprio(1);
#pragma unroll
    for (int m = 0; m < 4; ++m)
#pragma unroll
      for (int n = 0; n < 2; ++n) {
        acc[m][n + 2] = MFMA(aL[m][0], bH[n][0], acc[m][n + 2]);
        acc[m][n + 2] = MFMA(aL[m][1], bH[n][1], acc[m][n + 2]);
      }
    __builtin_amdgcn_s_setprio(0);
    __builtin_amdgcn_s_barrier();

    // ---- P3: read aH (m4-7); no stage (buf-c A still live) ----
#pragma unroll
    for (int m = 0; m < 4; ++m) {
      aH[m][0] = *reinterpret_cast<const short8*>(AsB + abase + aB + ((m + 4) << 11) + sx0);
      aH[m][1] = *reinterpret_cast<const short8*>(AsB + abase + aB + ((m + 4) << 11) + sx1);
    }
    __builtin_amdgcn_s_barrier();
    asm volatile("s_waitcnt lgkmcnt(0)" ::: "memory");
    __builtin_amdgcn_s_setprio(1);
#pragma unroll
    for (int m = 0; m < 4; ++m)
#pragma unroll
      for (int n = 0; n < 2; ++n) {
        acc[m + 4][n] = MFMA(aH[m][0], bL[n][0], acc[m + 4][n]);
        acc[m + 4][n] = MFMA(aH[m][1], bL[n][1], acc[m + 4][n]);
      }
    __builtin_amdgcn_s_setprio(0);
    __builtin_amdgcn_s_barrier();

    // ---- P4: stage (t+2, A-h0/h1); counted vmcnt; MFMA from regs ----
    STAGE(kt + 2, 0);
    STAGE(kt + 2, 1);
    if (kt < NT - 2) {
      asm volatile("s_waitcnt vmcnt(4)" ::: "memory");
    } else {
      asm volatile("s_waitcnt vmcnt(0)" ::: "memory");
    }
    __builtin_amdgcn_s_barrier();
    __builtin_amdgcn_s_setprio(1);
#pragma unroll
    for (int m = 0; m < 4; ++m)
#pragma unroll
      for (int n = 0; n < 2; ++n) {
        acc[m + 4][n + 2] = MFMA(aH[m][0], bH[n][0], acc[m + 4][n + 2]);
        acc[m + 4][n + 2] = MFMA(aH[m][1], bH[n][1], acc[m + 4][n + 2]);
      }
    __builtin_amdgcn_s_setprio(0);
    __builtin_amdgcn_s_barrier();
  }

  // ---- epilogue: lane holds all 4 gates (col-frags) for one column ----
  const int ng = (bx << 6) + (wc << 4) + l15;
  const float vbf = bf_[ng], vbi = bi_[ng], vbc = bc_[ng], vbo = bo_[ng];
#pragma unroll
  for (int m = 0; m < 8; ++m) {
#pragma unroll
    for (int r = 0; r < 4; ++r) {
      const int row = brow0 + (wr << 7) + (m << 4) + (l4 << 2) + r;
      const float fp = acc[m][0][r] + vbf;
      const float ip = acc[m][1][r] + vbi;
      const float gp = acc[m][2][r] + vbc;
      const float op = acc[m][3][r] + vbo;
      const float co = c_in[(size_t)row * NG + ng];
      const float cnew = co * sigm(fp) + sigm(ip) * tanh_fast(gp);
      out[(size_t)row * NG + ng] = tanh_fast(cnew) * sigm(op);
    }
  }
}

extern "C" void kernel_launch(void* const* d_in, const int* in_sizes, int n_in,
                              void* d_out, int out_size, void* d_ws, size_t ws_size,
                              hipStream_t stream) {
  const float* x   = (const float*)d_in[0];
  const float* h   = (const float*)d_in[1];
  const float* c   = (const float*)d_in[2];
  const float* w_f = (const float*)d_in[3];
  const float* b_f = (const float*)d_in[4];
  const float* w_i = (const float*)d_in[5];
  const float* b_i = (const float*)d_in[6];
  const float* w_c = (const float*)d_in[7];
  const float* b_c = (const float*)d_in[8];
  const float* w_o = (const float*)d_in[9];
  const float* b_o = (const float*)d_in[10];
  float* out = (float*)d_out;

  unsigned short* zh = (unsigned short*)d_ws;
  unsigned short* zl = zh + (size_t)NB * KZ;
  unsigned short* wh = zl + (size_t)NB * KZ;
  unsigned short* wl = wh + (size_t)KZ * 4096;

  zsplit_kernel<<<(NB * KZ / 4) / 256, 256, 0, stream>>>(x, h, zh, zl);
  wsplit_kernel<<<dim3(KZ / 32, NG / 32, 4), 256, 0, stream>>>(w_f, w_i, w_c, w_o, wh, wl);
  lstm_gemm256_kernel<<<dim3(16, 16), 512, 0, stream>>>(zh, zl, wh, wl, c,
                                                        b_f, b_i, b_c, b_o, out);
}

// Round 3
// 193.397 us; speedup vs baseline: 1.2498x; 1.0827x over previous
//
#include <hip/hip_runtime.h>
#include <hip/hip_bf16.h>

typedef short short8 __attribute__((ext_vector_type(8)));
typedef float f32x4 __attribute__((ext_vector_type(4)));

#define NB 4096   // batch rows
#define KZ 2048   // concat K (IN + OUT)
#define NG 1024   // per-gate output cols
#define NT 96     // K-tiles: 3 segments x (2048/64)

__device__ __forceinline__ unsigned short f2bf(float f) {
  unsigned int u = __float_as_uint(f);
  u += 0x7FFFu + ((u >> 16) & 1u);   // RNE
  return (unsigned short)(u >> 16);
}
__device__ __forceinline__ float bf2f(unsigned short s) {
  return __uint_as_float(((unsigned int)s) << 16);
}
__device__ __forceinline__ void gload_lds16(const void* g, void* l) {
  __builtin_amdgcn_global_load_lds(
      (__attribute__((address_space(1))) void*)g,
      (__attribute__((address_space(3))) void*)l, 16, 0, 0);
}
__device__ __forceinline__ float sigm(float x) { return 1.f / (1.f + __expf(-x)); }
__device__ __forceinline__ float tanh_fast(float x) {
  float e = __expf(-2.f * fabsf(x));
  float r = (1.f - e) / (1.f + e);
  return copysignf(r, x);
}

// ---- concat([x,h]) + bf16 hi/lo split -> zh/zl [4096][2048] ----
__global__ void zsplit_kernel(const float* __restrict__ x, const float* __restrict__ h,
                              unsigned short* __restrict__ zh, unsigned short* __restrict__ zl) {
  int idx = blockIdx.x * 256 + threadIdx.x;
  int e = idx << 2;
  int r = e >> 11;
  int k = e & (KZ - 1);
  const float* src = (k < 1024) ? (x + ((size_t)r << 10) + k)
                                : (h + ((size_t)r << 10) + (k - 1024));
  float4 v = *reinterpret_cast<const float4*>(src);
  float vf[4] = {v.x, v.y, v.z, v.w};
  unsigned short hh[4], ll[4];
#pragma unroll
  for (int j = 0; j < 4; ++j) {
    unsigned short hi = f2bf(vf[j]);
    unsigned short lo = f2bf(vf[j] - bf2f(hi));
    hh[j] = hi; ll[j] = lo;
  }
  uint2 H = make_uint2((unsigned)hh[0] | ((unsigned)hh[1] << 16),
                       (unsigned)hh[2] | ((unsigned)hh[3] << 16));
  uint2 L = make_uint2((unsigned)ll[0] | ((unsigned)ll[1] << 16),
                       (unsigned)ll[2] | ((unsigned)ll[3] << 16));
  *reinterpret_cast<uint2*>(zh + e) = H;
  *reinterpret_cast<uint2*>(zl + e) = L;
}

// ---- transpose + split weights into gate-interleaved packed rows ----
// p = (n>>6)<<8 | ((n>>4)&3)<<6 | g<<4 | (n&15)   (each wave's 64 cols = 4 gates x 16)
__global__ void wsplit_kernel(const float* __restrict__ w0, const float* __restrict__ w1,
                              const float* __restrict__ w2, const float* __restrict__ w3,
                              unsigned short* __restrict__ wh, unsigned short* __restrict__ wl) {
  __shared__ float tile[32][33];
  int g = blockIdx.z;
  const float* w = (g == 0) ? w0 : (g == 1) ? w1 : (g == 2) ? w2 : w3;
  int k0 = blockIdx.x << 5;
  int n0 = blockIdx.y << 5;
  int t = threadIdx.x;
  int rk = t >> 3, q = t & 7;
  float4 v = *reinterpret_cast<const float4*>(w + (size_t)(k0 + rk) * NG + n0 + (q << 2));
  tile[rk][(q << 2) + 0] = v.x;
  tile[rk][(q << 2) + 1] = v.y;
  tile[rk][(q << 2) + 2] = v.z;
  tile[rk][(q << 2) + 3] = v.w;
  __syncthreads();
  int n = t >> 3, kq = t & 7;
  unsigned short hs[4], ls[4];
#pragma unroll
  for (int j = 0; j < 4; ++j) {
    float f = tile[(kq << 2) + j][n];
    unsigned short hi = f2bf(f);
    unsigned short lo = f2bf(f - bf2f(hi));
    hs[j] = hi; ls[j] = lo;
  }
  int nn = n0 + n;
  int p = ((nn >> 6) << 8) | (((nn >> 4) & 3) << 6) | (g << 4) | (nn & 15);
  size_t o = (size_t)p * KZ + k0 + (kq << 2);
  uint2 H = make_uint2((unsigned)hs[0] | ((unsigned)hs[1] << 16),
                       (unsigned)hs[2] | ((unsigned)hs[3] << 16));
  uint2 L = make_uint2((unsigned)ls[0] | ((unsigned)ls[1] << 16),
                       (unsigned)ls[2] | ((unsigned)ls[3] << 16));
  *reinterpret_cast<uint2*>(wh + o) = H;
  *reinterpret_cast<uint2*>(wl + o) = L;
}

#define MFMA(a, b, c) __builtin_amdgcn_mfma_f32_16x16x32_bf16((a), (b), (c), 0, 0, 0)

// ---- 256x256 8-phase fused 4-gate GEMM + LSTM epilogue ----
// 8 waves (2M x 4N), per-wave 128x64; K = 3 segments x 2048, BK=64.
// Phases split by k-slot: reads 10/6/6/2 per phase; staging 1 half-tile/phase.
__global__ __launch_bounds__(512, 2) void lstm_gemm256_kernel(
    const unsigned short* __restrict__ zh, const unsigned short* __restrict__ zl,
    const unsigned short* __restrict__ wh, const unsigned short* __restrict__ wl,
    const float* __restrict__ c_in, const float* __restrict__ bf_,
    const float* __restrict__ bi_, const float* __restrict__ bc_,
    const float* __restrict__ bo_, float* __restrict__ out) {
  __shared__ unsigned short As[2 * 2 * 8192];   // 2 dbuf x 2 halves x 128x64, 64 KB
  __shared__ unsigned short Bs[2 * 2 * 8192];   // 64 KB
  const int t = threadIdx.x;
  const int lane = t & 63;
  const int wid = t >> 6;
  const int wr = wid >> 2;          // 0..1 (M)
  const int wc = wid & 3;           // 0..3 (N)
  const int l15 = lane & 15;
  const int l4 = lane >> 4;

  // XCD-aware bijective swizzle (256 blocks, 8 XCDs -> 32-block contiguous chunks)
  const int bid = blockIdx.x;
  const int swz = ((bid & 7) << 5) + (bid >> 3);
  const int bx = swz & 15;          // col-block
  const int by = swz >> 4;          // row-block
  const int brow0 = by << 8;
  const int pcol0 = bx << 8;

  char* AsB = (char*)As;
  char* BsB = (char*)Bs;

  // stage addressing: LDS linear dest, XOR slot-swizzled global source
  int aoff[2], boff[2];
#pragma unroll
  for (int j = 0; j < 2; ++j) {
    int row = (j << 6) + (t >> 3);
    int sl = (t & 7) ^ (row & 7);
    aoff[j] = (brow0 + row) * KZ + (sl << 3);
    boff[j] = (pcol0 + row) * KZ + (sl << 3);
  }
  const int ldsw = wid << 10;       // wave-uniform lane-base (HW adds lane*16)

  auto STAGE = [&](int s, int hx) {
    if (s >= NT) return;
    const int c = s & 1;
    const int seg = s >> 5;
    const int kk = (s & 31) << 6;
    if (hx < 2) {
      const unsigned short* src = (seg == 2) ? zl : zh;
      const int hb = hx * (128 * KZ);
      const int lb = c * 32768 + hx * 16384;
#pragma unroll
      for (int j = 0; j < 2; ++j)
        gload_lds16(src + aoff[j] + hb + kk, AsB + lb + (j << 13) + ldsw);
    } else {
      const unsigned short* src = (seg == 1) ? wl : wh;
      const int hb = (hx - 2) * (128 * KZ);
      const int lb = c * 32768 + (hx - 2) * 16384;
#pragma unroll
      for (int j = 0; j < 2; ++j)
        gload_lds16(src + boff[j] + hb + kk, BsB + lb + (j << 13) + ldsw);
    }
  };

  f32x4 acc[8][4];
#pragma unroll
  for (int m = 0; m < 8; ++m)
#pragma unroll
    for (int n = 0; n < 4; ++n) acc[m][n] = (f32x4){0.f, 0.f, 0.f, 0.f};

  // per-lane read constants
  const int rx = l15 & 7;
  const int sx0 = (l4 ^ rx) << 4;          // k-slot 0
  const int sx1 = ((4 + l4) ^ rx) << 4;    // k-slot 1
  const int aB = l15 << 7;                           // + m*2048
  const int bB = ((wc & 1) << 13) + (l15 << 7);      // + n*2048

  // prologue: tile0 (4 halves) + tile1 A-h0; steady-state invariant: 1 stage in flight
  STAGE(0, 0); STAGE(0, 1); STAGE(0, 2); STAGE(0, 3);
  STAGE(1, 0);
  asm volatile("s_waitcnt vmcnt(2)" ::: "memory");
  __builtin_amdgcn_s_barrier();

  for (int kt = 0; kt < NT; ++kt) {
    const int c = kt & 1;
    const int abase = c * 32768 + wr * 16384;
    const int bbase = c * 32768 + (wc >> 1) * 16384;
    short8 a0[8], a1[8], b0[4], b1[4];

    // ---- P1: read a0[0..7] + b0[0..1] (10); stage B(t+1)h0; MFMA n01 @ s0 ----
#pragma unroll
    for (int m = 0; m < 8; ++m)
      a0[m] = *reinterpret_cast<const short8*>(AsB + abase + aB + (m << 11) + sx0);
    b0[0] = *reinterpret_cast<const short8*>(BsB + bbase + bB + (0 << 11) + sx0);
    b0[1] = *reinterpret_cast<const short8*>(BsB + bbase + bB + (1 << 11) + sx0);
    STAGE(kt + 1, 2);
    asm volatile("s_waitcnt lgkmcnt(8)" ::: "memory");
    __builtin_amdgcn_s_barrier();
    asm volatile("s_waitcnt lgkmcnt(0)" ::: "memory");
    __builtin_amdgcn_s_setprio(1);
#pragma unroll
    for (int m = 0; m < 8; ++m) {
      acc[m][0] = MFMA(a0[m], b0[0], acc[m][0]);
      acc[m][1] = MFMA(a0[m], b0[1], acc[m][1]);
    }
    __builtin_amdgcn_s_setprio(0);
    __builtin_amdgcn_s_barrier();

    // ---- P2: read b0[2..3] + a1[0..3] (6); stage B(t+1)h1; MFMA n23 @ s0 ----
    b0[2] = *reinterpret_cast<const short8*>(BsB + bbase + bB + (2 << 11) + sx0);
    b0[3] = *reinterpret_cast<const short8*>(BsB + bbase + bB + (3 << 11) + sx0);
#pragma unroll
    for (int m = 0; m < 4; ++m)
      a1[m] = *reinterpret_cast<const short8*>(AsB + abase + aB + (m << 11) + sx1);
    STAGE(kt + 1, 3);
    __builtin_amdgcn_s_barrier();
    asm volatile("s_waitcnt lgkmcnt(0)" ::: "memory");
    __builtin_amdgcn_s_setprio(1);
#pragma unroll
    for (int m = 0; m < 8; ++m) {
      acc[m][2] = MFMA(a0[m], b0[2], acc[m][2]);
      acc[m][3] = MFMA(a0[m], b0[3], acc[m][3]);
    }
    __builtin_amdgcn_s_setprio(0);
    __builtin_amdgcn_s_barrier();

    // ---- P3: read a1[4..7] + b1[0..1] (6); stage A(t+1)h1; MFMA n01 @ s1 ----
#pragma unroll
    for (int m = 4; m < 8; ++m)
      a1[m] = *reinterpret_cast<const short8*>(AsB + abase + aB + (m << 11) + sx1);
    b1[0] = *reinterpret_cast<const short8*>(BsB + bbase + bB + (0 << 11) + sx1);
    b1[1] = *reinterpret_cast<const short8*>(BsB + bbase + bB + (1 << 11) + sx1);
    STAGE(kt + 1, 1);
    __builtin_amdgcn_s_barrier();
    asm volatile("s_waitcnt lgkmcnt(0)" ::: "memory");
    __builtin_amdgcn_s_setprio(1);
#pragma unroll
    for (int m = 0; m < 8; ++m) {
      acc[m][0] = MFMA(a1[m], b1[0], acc[m][0]);
      acc[m][1] = MFMA(a1[m], b1[1], acc[m][1]);
    }
    __builtin_amdgcn_s_setprio(0);
    __builtin_amdgcn_s_barrier();

    // ---- P4: read b1[2..3] (2); stage A(t+2)h0; counted vmcnt; MFMA n23 @ s1 ----
    b1[2] = *reinterpret_cast<const short8*>(BsB + bbase + bB + (2 << 11) + sx1);
    b1[3] = *reinterpret_cast<const short8*>(BsB + bbase + bB + (3 << 11) + sx1);
    STAGE(kt + 2, 0);
    if (kt < NT - 2) {
      asm volatile("s_waitcnt vmcnt(2)" ::: "memory");
    } else {
      asm volatile("s_waitcnt vmcnt(0)" ::: "memory");
    }
    __builtin_amdgcn_s_barrier();
    asm volatile("s_waitcnt lgkmcnt(0)" ::: "memory");
    __builtin_amdgcn_s_setprio(1);
#pragma unroll
    for (int m = 0; m < 8; ++m) {
      acc[m][2] = MFMA(a1[m], b1[2], acc[m][2]);
      acc[m][3] = MFMA(a1[m], b1[3], acc[m][3]);
    }
    __builtin_amdgcn_s_setprio(0);
    __builtin_amdgcn_s_barrier();
  }

  // ---- epilogue: lane holds all 4 gates (col-frags) for one column ----
  const int ng = (bx << 6) + (wc << 4) + l15;
  const float vbf = bf_[ng], vbi = bi_[ng], vbc = bc_[ng], vbo = bo_[ng];
#pragma unroll
  for (int m = 0; m < 8; ++m) {
#pragma unroll
    for (int r = 0; r < 4; ++r) {
      const int row = brow0 + (wr << 7) + (m << 4) + (l4 << 2) + r;
      const float fp = acc[m][0][r] + vbf;
      const float ip = acc[m][1][r] + vbi;
      const float gp = acc[m][2][r] + vbc;
      const float op = acc[m][3][r] + vbo;
      const float co = c_in[(size_t)row * NG + ng];
      const float cnew = co * sigm(fp) + sigm(ip) * tanh_fast(gp);
      out[(size_t)row * NG + ng] = tanh_fast(cnew) * sigm(op);
    }
  }
}

extern "C" void kernel_launch(void* const* d_in, const int* in_sizes, int n_in,
                              void* d_out, int out_size, void* d_ws, size_t ws_size,
                              hipStream_t stream) {
  const float* x   = (const float*)d_in[0];
  const float* h   = (const float*)d_in[1];
  const float* c   = (const float*)d_in[2];
  const float* w_f = (const float*)d_in[3];
  const float* b_f = (const float*)d_in[4];
  const float* w_i = (const float*)d_in[5];
  const float* b_i = (const float*)d_in[6];
  const float* w_c = (const float*)d_in[7];
  const float* b_c = (const float*)d_in[8];
  const float* w_o = (const float*)d_in[9];
  const float* b_o = (const float*)d_in[10];
  float* out = (float*)d_out;

  unsigned short* zh = (unsigned short*)d_ws;
  unsigned short* zl = zh + (size_t)NB * KZ;
  unsigned short* wh = zl + (size_t)NB * KZ;
  unsigned short* wl = wh + (size_t)KZ * 4096;

  zsplit_kernel<<<(NB * KZ / 4) / 256, 256, 0, stream>>>(x, h, zh, zl);
  wsplit_kernel<<<dim3(KZ / 32, NG / 32, 4), 256, 0, stream>>>(w_f, w_i, w_c, w_o, wh, wl);
  lstm_gemm256_kernel<<<256, 512, 0, stream>>>(zh, zl, wh, wl, c,
                                               b_f, b_i, b_c, b_o, out);
}

// Round 4
// 155.503 us; speedup vs baseline: 1.5544x; 1.2437x over previous
//
#include <hip/hip_runtime.h>
#include <hip/hip_bf16.h>

typedef short short8 __attribute__((ext_vector_type(8)));
typedef float f32x4 __attribute__((ext_vector_type(4)));

#define NB 4096   // batch rows
#define KZ 2048   // concat K (IN + OUT)
#define NG 1024   // per-gate output cols
#define NT 64     // K-tiles: 2 segments x (2048/64)

__device__ __forceinline__ unsigned short f2bf(float f) {
  unsigned int u = __float_as_uint(f);
  u += 0x7FFFu + ((u >> 16) & 1u);   // RNE
  return (unsigned short)(u >> 16);
}
__device__ __forceinline__ float bf2f(unsigned short s) {
  return __uint_as_float(((unsigned int)s) << 16);
}
__device__ __forceinline__ void gload_lds16(const void* g, void* l) {
  __builtin_amdgcn_global_load_lds(
      (__attribute__((address_space(1))) void*)g,
      (__attribute__((address_space(3))) void*)l, 16, 0, 0);
}
__device__ __forceinline__ float sigm(float x) { return 1.f / (1.f + __expf(-x)); }
__device__ __forceinline__ float tanh_fast(float x) {
  float e = __expf(-2.f * fabsf(x));
  float r = (1.f - e) / (1.f + e);
  return copysignf(r, x);
}

// ---- concat([x,h]) -> bf16 zh [4096][2048] (hi part only) ----
__global__ void zsplit_kernel(const float* __restrict__ x, const float* __restrict__ h,
                              unsigned short* __restrict__ zh) {
  int idx = blockIdx.x * 256 + threadIdx.x;
  int e = idx << 2;
  int r = e >> 11;
  int k = e & (KZ - 1);
  const float* src = (k < 1024) ? (x + ((size_t)r << 10) + k)
                                : (h + ((size_t)r << 10) + (k - 1024));
  float4 v = *reinterpret_cast<const float4*>(src);
  float vf[4] = {v.x, v.y, v.z, v.w};
  unsigned short hh[4];
#pragma unroll
  for (int j = 0; j < 4; ++j) hh[j] = f2bf(vf[j]);
  uint2 H = make_uint2((unsigned)hh[0] | ((unsigned)hh[1] << 16),
                       (unsigned)hh[2] | ((unsigned)hh[3] << 16));
  *reinterpret_cast<uint2*>(zh + e) = H;
}

// ---- transpose + hi/lo split weights into gate-interleaved packed rows ----
// p = (n>>6)<<8 | ((n>>4)&3)<<6 | g<<4 | (n&15)   (each wave's 64 cols = 4 gates x 16)
__global__ void wsplit_kernel(const float* __restrict__ w0, const float* __restrict__ w1,
                              const float* __restrict__ w2, const float* __restrict__ w3,
                              unsigned short* __restrict__ wh, unsigned short* __restrict__ wl) {
  __shared__ float tile[32][33];
  int g = blockIdx.z;
  const float* w = (g == 0) ? w0 : (g == 1) ? w1 : (g == 2) ? w2 : w3;
  int k0 = blockIdx.x << 5;
  int n0 = blockIdx.y << 5;
  int t = threadIdx.x;
  int rk = t >> 3, q = t & 7;
  float4 v = *reinterpret_cast<const float4*>(w + (size_t)(k0 + rk) * NG + n0 + (q << 2));
  tile[rk][(q << 2) + 0] = v.x;
  tile[rk][(q << 2) + 1] = v.y;
  tile[rk][(q << 2) + 2] = v.z;
  tile[rk][(q << 2) + 3] = v.w;
  __syncthreads();
  int n = t >> 3, kq = t & 7;
  unsigned short hs[4], ls[4];
#pragma unroll
  for (int j = 0; j < 4; ++j) {
    float f = tile[(kq << 2) + j][n];
    unsigned short hi = f2bf(f);
    unsigned short lo = f2bf(f - bf2f(hi));
    hs[j] = hi; ls[j] = lo;
  }
  int nn = n0 + n;
  int p = ((nn >> 6) << 8) | (((nn >> 4) & 3) << 6) | (g << 4) | (nn & 15);
  size_t o = (size_t)p * KZ + k0 + (kq << 2);
  uint2 H = make_uint2((unsigned)hs[0] | ((unsigned)hs[1] << 16),
                       (unsigned)hs[2] | ((unsigned)hs[3] << 16));
  uint2 L = make_uint2((unsigned)ls[0] | ((unsigned)ls[1] << 16),
                       (unsigned)ls[2] | ((unsigned)ls[3] << 16));
  *reinterpret_cast<uint2*>(wh + o) = H;
  *reinterpret_cast<uint2*>(wl + o) = L;
}

#define MFMA(a, b, c) __builtin_amdgcn_mfma_f32_16x16x32_bf16((a), (b), (c), 0, 0, 0)

// ---- 256x256 fused 4-gate GEMM + LSTM epilogue, 2-barrier rotated pipeline ----
// 8 waves (2M x 4N), per-wave 128x64; A = zh (both segs), B = wh then wl.
__global__ __launch_bounds__(512, 2) void lstm_gemm256_kernel(
    const unsigned short* __restrict__ zh,
    const unsigned short* __restrict__ wh, const unsigned short* __restrict__ wl,
    const float* __restrict__ c_in, const float* __restrict__ bf_,
    const float* __restrict__ bi_, const float* __restrict__ bc_,
    const float* __restrict__ bo_, float* __restrict__ out) {
  __shared__ unsigned short As[2 * 2 * 8192];   // 2 dbuf x 2 halves x 128x64, 64 KB
  __shared__ unsigned short Bs[2 * 2 * 8192];   // 64 KB
  const int t = threadIdx.x;
  const int lane = t & 63;
  const int wid = t >> 6;
  const int wr = wid >> 2;          // 0..1 (M)
  const int wc = wid & 3;           // 0..3 (N)
  const int l15 = lane & 15;
  const int l4 = lane >> 4;

  // XCD-aware bijective swizzle (256 blocks, 8 XCDs)
  const int bid = blockIdx.x;
  const int swz = ((bid & 7) << 5) + (bid >> 3);
  const int bx = swz & 15;
  const int by = swz >> 4;
  const int brow0 = by << 8;
  const int pcol0 = bx << 8;

  char* AsB = (char*)As;
  char* BsB = (char*)Bs;

  // stage addressing: LDS linear dest, XOR slot-swizzled global source
  int aoff[2], boff[2];
#pragma unroll
  for (int j = 0; j < 2; ++j) {
    int row = (j << 6) + (t >> 3);
    int sl = (t & 7) ^ (row & 7);
    aoff[j] = (brow0 + row) * KZ + (sl << 3);
    boff[j] = (pcol0 + row) * KZ + (sl << 3);
  }
  const int ldsw = wid << 10;       // wave-uniform lane-base (HW adds lane*16)

  auto STAGE = [&](int s, int hx) {
    if (s >= NT) return;
    const int c = s & 1;
    const int seg = s >> 5;         // 0: wh, 1: wl
    const int kk = (s & 31) << 6;
    if (hx < 2) {
      const int hb = hx * (128 * KZ);
      const int lb = c * 32768 + hx * 16384;
#pragma unroll
      for (int j = 0; j < 2; ++j)
        gload_lds16(zh + aoff[j] + hb + kk, AsB + lb + (j << 13) + ldsw);
    } else {
      const unsigned short* src = seg ? wl : wh;
      const int hb = (hx - 2) * (128 * KZ);
      const int lb = c * 32768 + (hx - 2) * 16384;
#pragma unroll
      for (int j = 0; j < 2; ++j)
        gload_lds16(src + boff[j] + hb + kk, BsB + lb + (j << 13) + ldsw);
    }
  };

  f32x4 acc[8][4];
#pragma unroll
  for (int m = 0; m < 8; ++m)
#pragma unroll
    for (int n = 0; n < 4; ++n) acc[m][n] = (f32x4){0.f, 0.f, 0.f, 0.f};

  // per-lane read constants
  const int rx = l15 & 7;
  const int sx0 = (l4 ^ rx) << 4;          // k-slot 0
  const int sx1 = ((4 + l4) ^ rx) << 4;    // k-slot 1
  const int aB = l15 << 7;                           // + m*2048
  const int bB = ((wc & 1) << 13) + (l15 << 7);      // + n*2048
  const int aW = wr << 14;                           // wave A-half base
  const int bW = (wc >> 1) << 14;                    // wave B-half base

  short8 a0[8], a1[8], b0[4], b1[4];

  // prologue: tile0 all 4 halves + tile1 A-h0; drain tile0; rotated reads for tile0
  STAGE(0, 0); STAGE(0, 1); STAGE(0, 2); STAGE(0, 3);
  STAGE(1, 0);
  asm volatile("s_waitcnt vmcnt(2)" ::: "memory");
  asm volatile("s_barrier" ::: "memory");
#pragma unroll
  for (int m = 0; m < 8; ++m)
    a0[m] = *reinterpret_cast<const short8*>(AsB + aW + aB + (m << 11) + sx0);
  b0[0] = *reinterpret_cast<const short8*>(BsB + bW + bB + (0 << 11) + sx0);
  b0[1] = *reinterpret_cast<const short8*>(BsB + bW + bB + (1 << 11) + sx0);

  for (int kt = 0; kt < NT; ++kt) {
    const int c = kt & 1;
    const int abase = c * 32768 + aW;
    const int bbase = c * 32768 + bW;
    const int anext = (c ^ 1) * 32768 + aW;
    const int bnext = (c ^ 1) * 32768 + bW;

    // ---- Phase A: stage B(t+1) h0,h1; read b0[2..3], a1[0..7], b1[0..1]; MFMA MG1
    STAGE(kt + 1, 2);
    STAGE(kt + 1, 3);
    b0[2] = *reinterpret_cast<const short8*>(BsB + bbase + bB + (2 << 11) + sx0);
    b0[3] = *reinterpret_cast<const short8*>(BsB + bbase + bB + (3 << 11) + sx0);
#pragma unroll
    for (int m = 0; m < 8; ++m)
      a1[m] = *reinterpret_cast<const short8*>(AsB + abase + aB + (m << 11) + sx1);
    b1[0] = *reinterpret_cast<const short8*>(BsB + bbase + bB + (0 << 11) + sx1);
    b1[1] = *reinterpret_cast<const short8*>(BsB + bbase + bB + (1 << 11) + sx1);
    __builtin_amdgcn_s_setprio(1);
#pragma unroll
    for (int m = 0; m < 8; ++m) {
      acc[m][0] = MFMA(a0[m], b0[0], acc[m][0]);
      acc[m][1] = MFMA(a0[m], b0[1], acc[m][1]);
    }
    __builtin_amdgcn_s_setprio(0);

    // ---- Phase B: stage A(t+1) h1; read b1[2..3]; MFMA MG2
    STAGE(kt + 1, 1);
    b1[2] = *reinterpret_cast<const short8*>(BsB + bbase + bB + (2 << 11) + sx1);
    b1[3] = *reinterpret_cast<const short8*>(BsB + bbase + bB + (3 << 11) + sx1);
    __builtin_amdgcn_s_setprio(1);
#pragma unroll
    for (int m = 0; m < 8; ++m) {
      acc[m][2] = MFMA(a0[m], b0[2], acc[m][2]);
      acc[m][3] = MFMA(a0[m], b0[3], acc[m][3]);
    }
    __builtin_amdgcn_s_setprio(0);

    // ---- Phase C: MFMA MG3 (k-slot 1)
    __builtin_amdgcn_s_setprio(1);
#pragma unroll
    for (int m = 0; m < 8; ++m) {
      acc[m][0] = MFMA(a1[m], b1[0], acc[m][0]);
      acc[m][1] = MFMA(a1[m], b1[1], acc[m][1]);
    }
    __builtin_amdgcn_s_setprio(0);
    asm volatile("s_barrier" ::: "memory");   // WAR: all waves consumed A-buf-c

    // ---- Phase D: stage A(t+2) h0; MFMA MG4; drain; rotated seam reads
    STAGE(kt + 2, 0);
    __builtin_amdgcn_s_setprio(1);
#pragma unroll
    for (int m = 0; m < 8; ++m) {
      acc[m][2] = MFMA(a1[m], b1[2], acc[m][2]);
      acc[m][3] = MFMA(a1[m], b1[3], acc[m][3]);
    }
    __builtin_amdgcn_s_setprio(0);
    if (kt < NT - 2) {
      asm volatile("s_waitcnt vmcnt(2)" ::: "memory");
    } else {
      asm volatile("s_waitcnt vmcnt(0)" ::: "memory");
    }
    asm volatile("s_barrier" ::: "memory");   // tile t+1 LDS complete for all waves
    if (kt < NT - 1) {
#pragma unroll
      for (int m = 0; m < 8; ++m)
        a0[m] = *reinterpret_cast<const short8*>(AsB + anext + aB + (m << 11) + sx0);
      b0[0] = *reinterpret_cast<const short8*>(BsB + bnext + bB + (0 << 11) + sx0);
      b0[1] = *reinterpret_cast<const short8*>(BsB + bnext + bB + (1 << 11) + sx0);
    }
  }

  // ---- epilogue: lane holds all 4 gates (col-frags) for one column ----
  const int ng = (bx << 6) + (wc << 4) + l15;
  const float vbf = bf_[ng], vbi = bi_[ng], vbc = bc_[ng], vbo = bo_[ng];
#pragma unroll
  for (int m = 0; m < 8; ++m) {
#pragma unroll
    for (int r = 0; r < 4; ++r) {
      const int row = brow0 + (wr << 7) + (m << 4) + (l4 << 2) + r;
      const float fp = acc[m][0][r] + vbf;
      const float ip = acc[m][1][r] + vbi;
      const float gp = acc[m][2][r] + vbc;
      const float op = acc[m][3][r] + vbo;
      const float co = c_in[(size_t)row * NG + ng];
      const float cnew = co * sigm(fp) + sigm(ip) * tanh_fast(gp);
      out[(size_t)row * NG + ng] = tanh_fast(cnew) * sigm(op);
    }
  }
}

extern "C" void kernel_launch(void* const* d_in, const int* in_sizes, int n_in,
                              void* d_out, int out_size, void* d_ws, size_t ws_size,
                              hipStream_t stream) {
  const float* x   = (const float*)d_in[0];
  const float* h   = (const float*)d_in[1];
  const float* c   = (const float*)d_in[2];
  const float* w_f = (const float*)d_in[3];
  const float* b_f = (const float*)d_in[4];
  const float* w_i = (const float*)d_in[5];
  const float* b_i = (const float*)d_in[6];
  const float* w_c = (const float*)d_in[7];
  const float* b_c = (const float*)d_in[8];
  const float* w_o = (const float*)d_in[9];
  const float* b_o = (const float*)d_in[10];
  float* out = (float*)d_out;

  unsigned short* zh = (unsigned short*)d_ws;                 // 16 MB
  unsigned short* wh = zh + (size_t)NB * KZ;                  // 16 MB
  unsigned short* wl = wh + (size_t)KZ * 4096;                // 16 MB

  zsplit_kernel<<<(NB * KZ / 4) / 256, 256, 0, stream>>>(x, h, zh);
  wsplit_kernel<<<dim3(KZ / 32, NG / 32, 4), 256, 0, stream>>>(w_f, w_i, w_c, w_o, wh, wl);
  lstm_gemm256_kernel<<<256, 512, 0, stream>>>(zh, wh, wl, c,
                                               b_f, b_i, b_c, b_o, out);
}

// Round 5
// 130.483 us; speedup vs baseline: 1.8524x; 1.1917x over previous
//
#include <hip/hip_runtime.h>
#include <hip/hip_bf16.h>

typedef short short8 __attribute__((ext_vector_type(8)));
typedef float f32x4 __attribute__((ext_vector_type(4)));

#define NB 4096   // batch rows
#define KZ 2048   // concat K (IN + OUT)
#define NG 1024   // per-gate output cols
#define NKS 32    // K-steps of 64; each macro-step does wh and wl sharing A

__device__ __forceinline__ unsigned short f2bf(float f) {
  unsigned int u = __float_as_uint(f);
  u += 0x7FFFu + ((u >> 16) & 1u);   // RNE
  return (unsigned short)(u >> 16);
}
__device__ __forceinline__ float bf2f(unsigned short s) {
  return __uint_as_float(((unsigned int)s) << 16);
}
__device__ __forceinline__ void gload_lds16(const void* g, void* l) {
  __builtin_amdgcn_global_load_lds(
      (__attribute__((address_space(1))) void*)g,
      (__attribute__((address_space(3))) void*)l, 16, 0, 0);
}
__device__ __forceinline__ float sigm(float x) { return 1.f / (1.f + __expf(-x)); }
__device__ __forceinline__ float tanh_fast(float x) {
  float e = __expf(-2.f * fabsf(x));
  float r = (1.f - e) / (1.f + e);
  return copysignf(r, x);
}

// ---- concat([x,h]) -> bf16 zh [4096][2048] ----
__global__ void zsplit_kernel(const float* __restrict__ x, const float* __restrict__ h,
                              unsigned short* __restrict__ zh) {
  int idx = blockIdx.x * 256 + threadIdx.x;
  int e = idx << 2;
  int r = e >> 11;
  int k = e & (KZ - 1);
  const float* src = (k < 1024) ? (x + ((size_t)r << 10) + k)
                                : (h + ((size_t)r << 10) + (k - 1024));
  float4 v = *reinterpret_cast<const float4*>(src);
  float vf[4] = {v.x, v.y, v.z, v.w};
  unsigned short hh[4];
#pragma unroll
  for (int j = 0; j < 4; ++j) hh[j] = f2bf(vf[j]);
  uint2 H = make_uint2((unsigned)hh[0] | ((unsigned)hh[1] << 16),
                       (unsigned)hh[2] | ((unsigned)hh[3] << 16));
  *reinterpret_cast<uint2*>(zh + e) = H;
}

// ---- transpose + hi/lo split weights into gate-interleaved packed rows ----
// p = (n>>6)<<8 | ((n>>4)&3)<<6 | g<<4 | (n&15)
__global__ void wsplit_kernel(const float* __restrict__ w0, const float* __restrict__ w1,
                              const float* __restrict__ w2, const float* __restrict__ w3,
                              unsigned short* __restrict__ wh, unsigned short* __restrict__ wl) {
  __shared__ float tile[32][33];
  int g = blockIdx.z;
  const float* w = (g == 0) ? w0 : (g == 1) ? w1 : (g == 2) ? w2 : w3;
  int k0 = blockIdx.x << 5;
  int n0 = blockIdx.y << 5;
  int t = threadIdx.x;
  int rk = t >> 3, q = t & 7;
  float4 v = *reinterpret_cast<const float4*>(w + (size_t)(k0 + rk) * NG + n0 + (q << 2));
  tile[rk][(q << 2) + 0] = v.x;
  tile[rk][(q << 2) + 1] = v.y;
  tile[rk][(q << 2) + 2] = v.z;
  tile[rk][(q << 2) + 3] = v.w;
  __syncthreads();
  int n = t >> 3, kq = t & 7;
  unsigned short hs[4], ls[4];
#pragma unroll
  for (int j = 0; j < 4; ++j) {
    float f = tile[(kq << 2) + j][n];
    unsigned short hi = f2bf(f);
    unsigned short lo = f2bf(f - bf2f(hi));
    hs[j] = hi; ls[j] = lo;
  }
  int nn = n0 + n;
  int p = ((nn >> 6) << 8) | (((nn >> 4) & 3) << 6) | (g << 4) | (nn & 15);
  size_t o = (size_t)p * KZ + k0 + (kq << 2);
  uint2 H = make_uint2((unsigned)hs[0] | ((unsigned)hs[1] << 16),
                       (unsigned)hs[2] | ((unsigned)hs[3] << 16));
  uint2 L = make_uint2((unsigned)ls[0] | ((unsigned)ls[1] << 16),
                       (unsigned)ls[2] | ((unsigned)ls[3] << 16));
  *reinterpret_cast<uint2*>(wh + o) = H;
  *reinterpret_cast<uint2*>(wl + o) = L;
}

#define MFMA(a, b, c) __builtin_amdgcn_mfma_f32_16x16x32_bf16((a), (b), (c), 0, 0, 0)
#define BAR() __builtin_amdgcn_s_barrier()
#define LGKM0() asm volatile("s_waitcnt lgkmcnt(0)" ::: "memory")
#define PRIO1() __builtin_amdgcn_s_setprio(1)
#define PRIO0() __builtin_amdgcn_s_setprio(0)

// ---- 256x256 macro-8-phase fused 4-gate GEMM + LSTM epilogue ----
// 8 waves (2M x 4N); per macro K-step (BK=64): A shared in regs across wh & wl tiles.
__global__ __launch_bounds__(512, 2) void lstm_gemm256_kernel(
    const unsigned short* __restrict__ zh,
    const unsigned short* __restrict__ wh, const unsigned short* __restrict__ wl,
    const float* __restrict__ c_in, const float* __restrict__ bf_,
    const float* __restrict__ bi_, const float* __restrict__ bc_,
    const float* __restrict__ bo_, float* __restrict__ out) {
  __shared__ unsigned short As[2 * 16384];   // 2 dbuf x (2 halves x 128x64) = 64 KB
  __shared__ unsigned short Bh[16384];       // wh tile, 32 KB
  __shared__ unsigned short Bl[16384];       // wl tile, 32 KB
  const int t = threadIdx.x;
  const int lane = t & 63;
  const int wid = t >> 6;
  const int wr = wid >> 2;          // 0..1 (M half)
  const int wc = wid & 3;           // 0..3 (N quarter)
  const int l15 = lane & 15;
  const int l4 = lane >> 4;

  // XCD-aware bijective swizzle (256 blocks, 8 XCDs)
  const int bid = blockIdx.x;
  const int swz = ((bid & 7) << 5) + (bid >> 3);
  const int bx = swz & 15;
  const int by = swz >> 4;
  const int brow0 = by << 8;
  const int pcol0 = bx << 8;

  char* AsB = (char*)As;
  char* BhB = (char*)Bh;
  char* BlB = (char*)Bl;

  // stage addressing: LDS linear dest, XOR slot-swizzled global source
  int aoff[2], boff[2];
#pragma unroll
  for (int j = 0; j < 2; ++j) {
    int row = (j << 6) + (t >> 3);
    int sl = (t & 7) ^ (row & 7);
    aoff[j] = (brow0 + row) * KZ + (sl << 3);
    boff[j] = (pcol0 + row) * KZ + (sl << 3);
  }
  const int ldsw = wid << 10;       // wave-uniform lane-base (HW adds lane*16)

  // hx: 0,1 = A halves (dbuf by ks&1); 2,3 = wh halves; 4,5 = wl halves
  auto STAGE = [&](int ks, int hx) {
    if (ks >= NKS) return;
    const int kk = ks << 6;
    if (hx < 2) {
      const int lb = ((ks & 1) << 15) + (hx << 14);
#pragma unroll
      for (int j = 0; j < 2; ++j)
        gload_lds16(zh + aoff[j] + hx * (128 * KZ) + kk, AsB + lb + (j << 13) + ldsw);
    } else if (hx < 4) {
      const int h = hx - 2;
#pragma unroll
      for (int j = 0; j < 2; ++j)
        gload_lds16(wh + boff[j] + h * (128 * KZ) + kk, BhB + (h << 14) + (j << 13) + ldsw);
    } else {
      const int h = hx - 4;
#pragma unroll
      for (int j = 0; j < 2; ++j)
        gload_lds16(wl + boff[j] + h * (128 * KZ) + kk, BlB + (h << 14) + (j << 13) + ldsw);
    }
  };

  f32x4 acc[8][4];
#pragma unroll
  for (int m = 0; m < 8; ++m)
#pragma unroll
    for (int n = 0; n < 4; ++n) acc[m][n] = (f32x4){0.f, 0.f, 0.f, 0.f};

  // per-lane read constants
  const int rx = l15 & 7;
  const int sx0 = (l4 ^ rx) << 4;          // k-slot 0
  const int sx1 = ((4 + l4) ^ rx) << 4;    // k-slot 1
  const int aB = l15 << 7;                           // + m*2048
  const int bB = ((wc & 1) << 13) + (l15 << 7);      // + n*2048
  const int aW = wr << 14;                           // wave A-half base
  const int bW = (wc >> 1) << 14;                    // wave B-half base

  short8 a0[8], a1[8], bh0[4], bh1[4], bl0[4], bl1[4];

  // prologue: A@0, wh@0, wl@0 (12 loads); drain A+wh, leave wl in flight
  STAGE(0, 0); STAGE(0, 1); STAGE(0, 2); STAGE(0, 3); STAGE(0, 4); STAGE(0, 5);
  asm volatile("s_waitcnt vmcnt(4)" ::: "memory");
  BAR();

  for (int ks = 0; ks < NKS; ++ks) {
    const int abase = ((ks & 1) << 15) + aW;
    const bool last = (ks == NKS - 1);

    // ---- P1: read a0[0..3], bh0[0..3]; MFMA m0-3 x bh0 ----
#pragma unroll
    for (int m = 0; m < 4; ++m)
      a0[m] = *reinterpret_cast<const short8*>(AsB + abase + aB + (m << 11) + sx0);
#pragma unroll
    for (int n = 0; n < 4; ++n)
      bh0[n] = *reinterpret_cast<const short8*>(BhB + bW + bB + (n << 11) + sx0);
    BAR(); LGKM0(); PRIO1();
#pragma unroll
    for (int m = 0; m < 4; ++m)
#pragma unroll
      for (int n = 0; n < 4; ++n) acc[m][n] = MFMA(a0[m], bh0[n], acc[m][n]);
    PRIO0(); BAR();

    // ---- P2: read a0[4..7]; MFMA m4-7 x bh0 ----
#pragma unroll
    for (int m = 4; m < 8; ++m)
      a0[m] = *reinterpret_cast<const short8*>(AsB + abase + aB + (m << 11) + sx0);
    BAR(); LGKM0(); PRIO1();
#pragma unroll
    for (int m = 0; m < 4; ++m)
#pragma unroll
      for (int n = 0; n < 4; ++n) acc[m + 4][n] = MFMA(a0[m + 4], bh0[n], acc[m + 4][n]);
    PRIO0(); BAR();

    // ---- P3: read a1[0..3], bh1[0..3]; stage A'(h0); MFMA m0-3 x bh1 ----
#pragma unroll
    for (int m = 0; m < 4; ++m)
      a1[m] = *reinterpret_cast<const short8*>(AsB + abase + aB + (m << 11) + sx1);
#pragma unroll
    for (int n = 0; n < 4; ++n)
      bh1[n] = *reinterpret_cast<const short8*>(BhB + bW + bB + (n << 11) + sx1);
    STAGE(ks + 1, 0);
    BAR(); LGKM0(); PRIO1();
#pragma unroll
    for (int m = 0; m < 4; ++m)
#pragma unroll
      for (int n = 0; n < 4; ++n) acc[m][n] = MFMA(a1[m], bh1[n], acc[m][n]);
    PRIO0(); BAR();

    // ---- P4: read a1[4..7]; stage A'(h1); drain wl@ks; MFMA m4-7 x bh1 ----
#pragma unroll
    for (int m = 4; m < 8; ++m)
      a1[m] = *reinterpret_cast<const short8*>(AsB + abase + aB + (m << 11) + sx1);
    STAGE(ks + 1, 1);
    if (!last) { asm volatile("s_waitcnt vmcnt(4)" ::: "memory"); }
    else       { asm volatile("s_waitcnt vmcnt(0)" ::: "memory"); }
    BAR(); LGKM0(); PRIO1();
#pragma unroll
    for (int m = 0; m < 4; ++m)
#pragma unroll
      for (int n = 0; n < 4; ++n) acc[m + 4][n] = MFMA(a1[m + 4], bh1[n], acc[m + 4][n]);
    PRIO0(); BAR();

    // ---- P5: read bl0[0..3]; stage wh'(h0); MFMA m0-3 x bl0 ----
#pragma unroll
    for (int n = 0; n < 4; ++n)
      bl0[n] = *reinterpret_cast<const short8*>(BlB + bW + bB + (n << 11) + sx0);
    STAGE(ks + 1, 2);
    BAR(); LGKM0(); PRIO1();
#pragma unroll
    for (int m = 0; m < 4; ++m)
#pragma unroll
      for (int n = 0; n < 4; ++n) acc[m][n] = MFMA(a0[m], bl0[n], acc[m][n]);
    PRIO0(); BAR();

    // ---- P6: read bl1[0..3]; stage wh'(h1); MFMA m4-7 x bl0 ----
#pragma unroll
    for (int n = 0; n < 4; ++n)
      bl1[n] = *reinterpret_cast<const short8*>(BlB + bW + bB + (n << 11) + sx1);
    STAGE(ks + 1, 3);
    BAR(); LGKM0(); PRIO1();
#pragma unroll
    for (int m = 0; m < 4; ++m)
#pragma unroll
      for (int n = 0; n < 4; ++n) acc[m + 4][n] = MFMA(a0[m + 4], bl0[n], acc[m + 4][n]);
    PRIO0(); BAR();

    // ---- P7: stage wl'(h0); MFMA m0-3 x bl1 ----
    STAGE(ks + 1, 4);
    BAR(); PRIO1();
#pragma unroll
    for (int m = 0; m < 4; ++m)
#pragma unroll
      for (int n = 0; n < 4; ++n) acc[m][n] = MFMA(a1[m], bl1[n], acc[m][n]);
    PRIO0(); BAR();

    // ---- P8: stage wl'(h1); drain A'+wh'; MFMA m4-7 x bl1 ----
    STAGE(ks + 1, 5);
    if (!last) { asm volatile("s_waitcnt vmcnt(4)" ::: "memory"); }
    BAR(); PRIO1();
#pragma unroll
    for (int m = 0; m < 4; ++m)
#pragma unroll
      for (int n = 0; n < 4; ++n) acc[m + 4][n] = MFMA(a1[m + 4], bl1[n], acc[m + 4][n]);
    PRIO0(); BAR();
  }

  // ---- epilogue: lane holds all 4 gates (col-frags) for one column ----
  const int ng = (bx << 6) + (wc << 4) + l15;
  const float vbf = bf_[ng], vbi = bi_[ng], vbc = bc_[ng], vbo = bo_[ng];
#pragma unroll
  for (int m = 0; m < 8; ++m) {
#pragma unroll
    for (int r = 0; r < 4; ++r) {
      const int row = brow0 + (wr << 7) + (m << 4) + (l4 << 2) + r;
      const float fp = acc[m][0][r] + vbf;
      const float ip = acc[m][1][r] + vbi;
      const float gp = acc[m][2][r] + vbc;
      const float op = acc[m][3][r] + vbo;
      const float co = c_in[(size_t)row * NG + ng];
      const float cnew = co * sigm(fp) + sigm(ip) * tanh_fast(gp);
      out[(size_t)row * NG + ng] = tanh_fast(cnew) * sigm(op);
    }
  }
}

extern "C" void kernel_launch(void* const* d_in, const int* in_sizes, int n_in,
                              void* d_out, int out_size, void* d_ws, size_t ws_size,
                              hipStream_t stream) {
  const float* x   = (const float*)d_in[0];
  const float* h   = (const float*)d_in[1];
  const float* c   = (const float*)d_in[2];
  const float* w_f = (const float*)d_in[3];
  const float* b_f = (const float*)d_in[4];
  const float* w_i = (const float*)d_in[5];
  const float* b_i = (const float*)d_in[6];
  const float* w_c = (const float*)d_in[7];
  const float* b_c = (const float*)d_in[8];
  const float* w_o = (const float*)d_in[9];
  const float* b_o = (const float*)d_in[10];
  float* out = (float*)d_out;

  unsigned short* zh = (unsigned short*)d_ws;                 // 16 MB
  unsigned short* wh = zh + (size_t)NB * KZ;                  // 16 MB
  unsigned short* wl = wh + (size_t)KZ * 4096;                // 16 MB

  zsplit_kernel<<<(NB * KZ / 4) / 256, 256, 0, stream>>>(x, h, zh);
  wsplit_kernel<<<dim3(KZ / 32, NG / 32, 4), 256, 0, stream>>>(w_f, w_i, w_c, w_o, wh, wl);
  lstm_gemm256_kernel<<<256, 512, 0, stream>>>(zh, wh, wl, c,
                                               b_f, b_i, b_c, b_o, out);
}